// Round 8
// baseline (103.353 us; speedup 1.0000x reference)
//
#include <hip/hip_runtime.h>

#define N 2048
#define T 32
#define D 128
#define BT 32
#define MT (N / BT)                // 64 row-blocks
#define NTILES (MT * (MT + 1) / 2) // 2080 upper-triangular 32x32 tiles
#define NWAVES (2 * NTILES)        // 4160 half-tile (16x32) waves
#define NBLK (NWAVES / 4)          // 1040 blocks x 256 threads
#define PSTR 33                    // LDS row stride (32 data + 1) — bank m+c per row m

typedef float floatx4 __attribute__((ext_vector_type(4)));
typedef short bf16x8 __attribute__((ext_vector_type(8)));

// s_waitcnt lgkmcnt(0) only — 0xc07f. Per-wave LDS regions: no barrier needed
// until the final block reduction.
#define LGKM0() __builtin_amdgcn_s_waitcnt(0xc07f)

// fp32 -> truncated-bf16 high + truncated-bf16 of exact remainder.
// Gram via hh+hl+lh drops only ll (<=2^-16 rel) — absmax 0.0 in R5-R7.
__device__ __forceinline__ void split8(float4 a, float4 b, bf16x8& h, bf16x8& l) {
  float v[8] = {a.x, a.y, a.z, a.w, b.x, b.y, b.z, b.w};
#pragma unroll
  for (int i = 0; i < 8; ++i) {
    unsigned u = __float_as_uint(v[i]);
    h[i] = (short)(u >> 16);
    float lo = v[i] - __uint_as_float(u & 0xffff0000u);
    l[i] = (short)(__float_as_uint(lo) >> 16);
  }
}

__device__ __forceinline__ float sumsq8(float4 a, float4 b) {
  return a.x * a.x + a.y * a.y + a.z * a.z + a.w * a.w +
         b.x * b.x + b.y * b.y + b.z * b.z + b.w * b.w;
}

// tile id -> (a,b), a<=b, upper-triangular over MT x MT
__device__ __forceinline__ void tile_decode(int t, int& a, int& b) {
  a = (int)((2 * MT + 1 -
             sqrtf((float)((2 * MT + 1) * (2 * MT + 1) - 8 * t))) * 0.5f);
  while (a > 0 && t < a * MT - a * (a - 1) / 2) --a;
  while (t >= (a + 1) * MT - (a + 1) * a / 2) ++a;
  b = a + (t - (a * MT - a * (a - 1) / 2));
}

// ---------------------------------------------------------------------------
// Single fused kernel. Each WAVE owns a 16x32 half-tile: A-rows
// aRow0+16h..+16, all 32 B-rows. 4160 waves (~4/SIMD — 2x R5's latency
// hiding). Per wave: stage 48 pred rows in private LDS, 24 loads + split +
// 24 MFMA for the Gram, norms via quad shuffles, hinge sum_t max(|dp|,s)
// with -32s correction under the k>j mask. Block-reduce -> one double
// atomicAdd; completion counter; last block finalizes the scalar.
// ---------------------------------------------------------------------------
__global__ __launch_bounds__(256) void fused_kernel(
    const float* __restrict__ pred,     // [N][T]
    const float* __restrict__ X,        // [N][D]
    const float* __restrict__ scale_p,  // [1]
    const float* __restrict__ target,   // [1]
    double* __restrict__ acc,           // ws+0  (zeroed by memset)
    unsigned* __restrict__ counter,     // ws+8  (zeroed by memset)
    float* __restrict__ out) {
  __shared__ float P[4][48 * PSTR];     // per-wave: 16 A-pred rows + 32 B-pred rows
  __shared__ float nrmA[4][16], nrmB[4][32];
  __shared__ double red[4];

  const int tid  = threadIdx.x;
  const int wid  = tid >> 6;
  const int lane = tid & 63;
  const int w    = blockIdx.x * 4 + wid;  // 0..NWAVES-1
  const int tile = w >> 1;
  const int h    = w & 1;                 // half: A-rows 16h..16h+16

  int a, b;
  tile_decode(tile, a, b);
  const int aRow0 = a * BT, bRow0 = b * BT;
  const int m    = lane & 15;
  const int quad = lane >> 4;
  const float scale = scale_p[0];

  // ---- stage 48 pred rows (16 A + 32 B) into this wave's LDS region.
  //      384 float4 slots / 64 lanes = 6 each; coalesced per 8-lane row group.
#pragma unroll
  for (int s = 0; s < 6; ++s) {
    const int idx = s * 64 + lane;
    const int row = idx >> 3;
    const int fo  = (idx & 7) * 4;
    const int grow = (row < 16) ? (aRow0 + 16 * h + row) : (bRow0 + row - 16);
    *(float4*)(&P[wid][row * PSTR + fo]) =
        *(const float4*)(pred + (size_t)grow * T + fo);
  }

  // ---- Gram half-tile: C[16x32] = Xa_half . Xb^T via split-bf16 MFMA
  floatx4 accf[2];
  accf[0] = (floatx4){0.f, 0.f, 0.f, 0.f};
  accf[1] = (floatx4){0.f, 0.f, 0.f, 0.f};
  float ssA = 0.f, ssB[2] = {0.f, 0.f};

  const float* xar = X + (size_t)(aRow0 + 16 * h + m) * D + quad * 8;
  const float* xb0 = X + (size_t)(bRow0 + m) * D + quad * 8;

#pragma unroll
  for (int ks = 0; ks < 4; ++ks) {
    bf16x8 hA, lA, hB[2], lB[2];
    {
      float4 u0 = *(const float4*)(xar + ks * 32);
      float4 u1 = *(const float4*)(xar + ks * 32 + 4);
      ssA += sumsq8(u0, u1);
      split8(u0, u1, hA, lA);
    }
#pragma unroll
    for (int J = 0; J < 2; ++J) {
      float4 w0 = *(const float4*)(xb0 + (size_t)J * 16 * D + ks * 32);
      float4 w1 = *(const float4*)(xb0 + (size_t)J * 16 * D + ks * 32 + 4);
      ssB[J] += sumsq8(w0, w1);
      split8(w0, w1, hB[J], lB[J]);
    }
#pragma unroll
    for (int J = 0; J < 2; ++J) {
      accf[J] = __builtin_amdgcn_mfma_f32_16x16x32_bf16(hA, hB[J], accf[J], 0, 0, 0);
      accf[J] = __builtin_amdgcn_mfma_f32_16x16x32_bf16(hA, lB[J], accf[J], 0, 0, 0);
      accf[J] = __builtin_amdgcn_mfma_f32_16x16x32_bf16(lA, hB[J], accf[J], 0, 0, 0);
    }
  }

  // ---- norms: reduce row partials across the 4 quads
  ssA += __shfl_xor(ssA, 16, 64);
  ssA += __shfl_xor(ssA, 32, 64);
#pragma unroll
  for (int J = 0; J < 2; ++J) {
    ssB[J] += __shfl_xor(ssB[J], 16, 64);
    ssB[J] += __shfl_xor(ssB[J], 32, 64);
  }
  if (quad == 0) {
    nrmA[wid][m] = rsqrtf(ssA);
    nrmB[wid][m]      = rsqrtf(ssB[0]);
    nrmB[wid][16 + m] = rsqrtf(ssB[1]);
  }
  LGKM0();  // wave-private LDS: lgkmcnt(0) suffices (DS in-order per wave)

  // ---- sd = scale*(1 - G*na*nb) in C layout: row = quad*4+r, col = 16J+m
  float na[4], nb[2];
#pragma unroll
  for (int r = 0; r < 4; ++r) na[r] = nrmA[wid][quad * 4 + r];
  nb[0] = nrmB[wid][m];
  nb[1] = nrmB[wid][16 + m];

  float sd[2][4], ps[2][4];
#pragma unroll
  for (int J = 0; J < 2; ++J)
#pragma unroll
    for (int r = 0; r < 4; ++r) {
      sd[J][r] = scale * (1.0f - accf[J][r] * na[r] * nb[J]);
      ps[J][r] = 0.0f;
    }

  // ---- hinge: sum_t max(|dp|, s); -32s correction under the mask.
  //      qa: 16-lane broadcast rows; qb: stride-33 rows -> conflict-free.
#pragma unroll
  for (int t4 = 0; t4 < 8; ++t4) {
    float4 qb[2];
    qb[0] = *(const float4*)(&P[wid][(16 + m) * PSTR + t4 * 4]);
    qb[1] = *(const float4*)(&P[wid][(32 + m) * PSTR + t4 * 4]);
#pragma unroll
    for (int r = 0; r < 4; ++r) {
      float4 qa = *(const float4*)(&P[wid][(quad * 4 + r) * PSTR + t4 * 4]);
#pragma unroll
      for (int J = 0; J < 2; ++J) {
        float s = sd[J][r];
        ps[J][r] += fmaxf(fabsf(qa.x - qb[J].x), s) +
                    fmaxf(fabsf(qa.y - qb[J].y), s) +
                    fmaxf(fabsf(qa.z - qb[J].z), s) +
                    fmaxf(fabsf(qa.w - qb[J].w), s);
      }
    }
  }

  // ---- mask + correction + wave reduction
  float tsum = 0.0f;
#pragma unroll
  for (int J = 0; J < 2; ++J)
#pragma unroll
    for (int r = 0; r < 4; ++r) {
      const int ja   = aRow0 + 16 * h + quad * 4 + r;
      const int kcol = bRow0 + 16 * J + m;
      tsum += (kcol > ja) ? (ps[J][r] - 32.0f * sd[J][r]) : 0.0f;
    }

  double dsum = (double)tsum;
#pragma unroll
  for (int off = 32; off > 0; off >>= 1) dsum += __shfl_down(dsum, off, 64);
  if (lane == 0) red[wid] = dsum;
  __syncthreads();

  if (tid == 0) {
    const double blksum = red[0] + red[1] + red[2] + red[3];
    atomicAdd(acc, blksum);
    __threadfence();
    const unsigned done = atomicAdd(counter, 1u);
    if (done == NBLK - 1) {  // last block finalizes
      const double tot = atomicAdd(acc, 0.0);  // atomic read (device scope)
      const double mf  = 2.0 * tot / ((double)N * (double)(N - 1) * (double)T);
      const double r   = mf - (double)target[0];
      out[0] = (float)(r > 0.0 ? r : 0.0);
    }
  }
}

extern "C" void kernel_launch(void* const* d_in, const int* in_sizes, int n_in,
                              void* d_out, int out_size, void* d_ws, size_t ws_size,
                              hipStream_t stream) {
  const float* target = (const float*)d_in[0];
  const float* pred   = (const float*)d_in[1];
  const float* X      = (const float*)d_in[2];
  // d_in[3] = ntimes (==32, hardcoded); d_in[4] = scale
  const float* scale  = (const float*)d_in[4];

  double*   acc     = (double*)d_ws;                 // ws+0
  unsigned* counter = (unsigned*)((char*)d_ws + 8);  // ws+8

  hipMemsetAsync(d_ws, 0, 16, stream);  // zero acc + counter (ws is poisoned)
  fused_kernel<<<dim3(NBLK), dim3(256), 0, stream>>>(
      pred, X, scale, target, acc, counter, (float*)d_out);
}

// Round 9
// 86.961 us; speedup vs baseline: 1.1885x; 1.1885x over previous
//
#include <hip/hip_runtime.h>

#define N 2048
#define T 32
#define D 128
#define BT 32
#define MT (N / BT)                // 64 row-blocks
#define NTILES (MT * (MT + 1) / 2) // 2080 upper-triangular 32x32 tiles
#define NWAVES (2 * NTILES)        // 4160 half-tile (16x32) single-wave blocks
#define PSTR 33                    // LDS row stride (32 data + 1)

typedef float floatx4 __attribute__((ext_vector_type(4)));
typedef short bf16x8 __attribute__((ext_vector_type(8)));

// s_waitcnt lgkmcnt(0) only — 0xc07f. Single-wave WG: no barrier ever.
#define LGKM0() __builtin_amdgcn_s_waitcnt(0xc07f)

// fp32 -> truncated-bf16 high + truncated-bf16 of exact remainder.
// Gram via hh+hl+lh drops only ll (<=2^-16 rel) — absmax 0.0 in R5-R8.
__device__ __forceinline__ void split8(float4 a, float4 b, bf16x8& h, bf16x8& l) {
  float v[8] = {a.x, a.y, a.z, a.w, b.x, b.y, b.z, b.w};
#pragma unroll
  for (int i = 0; i < 8; ++i) {
    unsigned u = __float_as_uint(v[i]);
    h[i] = (short)(u >> 16);
    float lo = v[i] - __uint_as_float(u & 0xffff0000u);
    l[i] = (short)(__float_as_uint(lo) >> 16);
  }
}

__device__ __forceinline__ float sumsq8(float4 a, float4 b) {
  return a.x * a.x + a.y * a.y + a.z * a.z + a.w * a.w +
         b.x * b.x + b.y * b.y + b.z * b.z + b.w * b.w;
}

// tile id -> (a,b), a<=b, upper-triangular over MT x MT
__device__ __forceinline__ void tile_decode(int t, int& a, int& b) {
  a = (int)((2 * MT + 1 -
             sqrtf((float)((2 * MT + 1) * (2 * MT + 1) - 8 * t))) * 0.5f);
  while (a > 0 && t < a * MT - a * (a - 1) / 2) --a;
  while (t >= (a + 1) * MT - (a + 1) * a / 2) ++a;
  b = a + (t - (a * MT - a * (a - 1) / 2));
}

// ---------------------------------------------------------------------------
// Pair kernel: one 16x32 half-tile per single-wave (64-thread) block.
// 4160 blocks -> ~4 waves/SIMD (2x R5). Identical numerics to R5/R8.
// NO atomics / NO completion counter / NO __syncthreads (R8's 1040
// same-address device atomicAdds were the suspected 19-µs serialization):
// per-block partials to distinct addresses, separate finalize dispatch.
// ---------------------------------------------------------------------------
__global__ __launch_bounds__(64) void pair_kernel(
    const float* __restrict__ pred,     // [N][T]
    const float* __restrict__ X,        // [N][D]
    const float* __restrict__ scale_p,  // [1]
    double* __restrict__ partials) {    // [NWAVES]
  __shared__ float P[48 * PSTR];        // 16 A-pred rows + 32 B-pred rows
  __shared__ float nrmA[16], nrmB[32];

  const int lane = threadIdx.x;
  const int w    = blockIdx.x;
  const int tile = w >> 1;
  const int h    = w & 1;               // half: A-rows 16h..16h+15

  int a, b;
  tile_decode(tile, a, b);
  const int aRow0 = a * BT, bRow0 = b * BT;
  const int m    = lane & 15;
  const int quad = lane >> 4;
  const float scale = scale_p[0];

  // ---- stage 48 pred rows: 384 float4 chunks / 64 lanes = 6 each
#pragma unroll
  for (int s = 0; s < 6; ++s) {
    const int idx = s * 64 + lane;
    const int row = idx >> 3;
    const int fo  = (idx & 7) * 4;
    const int grow = (row < 16) ? (aRow0 + 16 * h + row) : (bRow0 + row - 16);
    *(float4*)(&P[row * PSTR + fo]) =
        *(const float4*)(pred + (size_t)grow * T + fo);
  }

  // ---- Gram half-tile: C[16x32] = Xa_half . Xb^T via split-bf16 MFMA
  floatx4 accf[2];
  accf[0] = (floatx4){0.f, 0.f, 0.f, 0.f};
  accf[1] = (floatx4){0.f, 0.f, 0.f, 0.f};
  float ssA = 0.f, ssB[2] = {0.f, 0.f};

  const float* xar = X + (size_t)(aRow0 + 16 * h + m) * D + quad * 8;
  const float* xb0 = X + (size_t)(bRow0 + m) * D + quad * 8;

#pragma unroll
  for (int ks = 0; ks < 4; ++ks) {
    bf16x8 hA, lA, hB[2], lB[2];
    {
      float4 u0 = *(const float4*)(xar + ks * 32);
      float4 u1 = *(const float4*)(xar + ks * 32 + 4);
      ssA += sumsq8(u0, u1);
      split8(u0, u1, hA, lA);
    }
#pragma unroll
    for (int J = 0; J < 2; ++J) {
      float4 w0 = *(const float4*)(xb0 + (size_t)J * 16 * D + ks * 32);
      float4 w1 = *(const float4*)(xb0 + (size_t)J * 16 * D + ks * 32 + 4);
      ssB[J] += sumsq8(w0, w1);
      split8(w0, w1, hB[J], lB[J]);
    }
#pragma unroll
    for (int J = 0; J < 2; ++J) {
      accf[J] = __builtin_amdgcn_mfma_f32_16x16x32_bf16(hA, hB[J], accf[J], 0, 0, 0);
      accf[J] = __builtin_amdgcn_mfma_f32_16x16x32_bf16(hA, lB[J], accf[J], 0, 0, 0);
      accf[J] = __builtin_amdgcn_mfma_f32_16x16x32_bf16(lA, hB[J], accf[J], 0, 0, 0);
    }
  }

  // ---- norms: reduce row partials across the 4 quads
  ssA += __shfl_xor(ssA, 16, 64);
  ssA += __shfl_xor(ssA, 32, 64);
#pragma unroll
  for (int J = 0; J < 2; ++J) {
    ssB[J] += __shfl_xor(ssB[J], 16, 64);
    ssB[J] += __shfl_xor(ssB[J], 32, 64);
  }
  if (quad == 0) {
    nrmA[m]      = rsqrtf(ssA);
    nrmB[m]      = rsqrtf(ssB[0]);
    nrmB[16 + m] = rsqrtf(ssB[1]);
  }
  LGKM0();  // single wave: DS in-order, no barrier needed

  // ---- sd = scale*(1 - G*na*nb); C layout: row = quad*4+r, col = 16J+m
  float na[4], nb[2];
#pragma unroll
  for (int r = 0; r < 4; ++r) na[r] = nrmA[quad * 4 + r];
  nb[0] = nrmB[m];
  nb[1] = nrmB[16 + m];

  float sd[2][4], ps[2][4];
#pragma unroll
  for (int J = 0; J < 2; ++J)
#pragma unroll
    for (int r = 0; r < 4; ++r) {
      sd[J][r] = scale * (1.0f - accf[J][r] * na[r] * nb[J]);
      ps[J][r] = 0.0f;
    }

  // ---- hinge: sum_t max(|dp|, s); -32s correction under the mask
#pragma unroll
  for (int t4 = 0; t4 < 8; ++t4) {
    float4 qb[2];
    qb[0] = *(const float4*)(&P[(16 + m) * PSTR + t4 * 4]);
    qb[1] = *(const float4*)(&P[(32 + m) * PSTR + t4 * 4]);
#pragma unroll
    for (int r = 0; r < 4; ++r) {
      float4 qa = *(const float4*)(&P[(quad * 4 + r) * PSTR + t4 * 4]);
#pragma unroll
      for (int J = 0; J < 2; ++J) {
        float s = sd[J][r];
        ps[J][r] += fmaxf(fabsf(qa.x - qb[J].x), s) +
                    fmaxf(fabsf(qa.y - qb[J].y), s) +
                    fmaxf(fabsf(qa.z - qb[J].z), s) +
                    fmaxf(fabsf(qa.w - qb[J].w), s);
      }
    }
  }

  // ---- mask + correction + wave reduction
  float tsum = 0.0f;
#pragma unroll
  for (int J = 0; J < 2; ++J)
#pragma unroll
    for (int r = 0; r < 4; ++r) {
      const int ja   = aRow0 + 16 * h + quad * 4 + r;
      const int kcol = bRow0 + 16 * J + m;
      tsum += (kcol > ja) ? (ps[J][r] - 32.0f * sd[J][r]) : 0.0f;
    }

  double dsum = (double)tsum;
#pragma unroll
  for (int off = 32; off > 0; off >>= 1) dsum += __shfl_down(dsum, off, 64);
  if (lane == 0) partials[w] = dsum;
}

// ---------------------------------------------------------------------------
// Finalize: sum NWAVES partials, scale, clamp.
// ---------------------------------------------------------------------------
__global__ __launch_bounds__(256) void finalize_kernel(
    const double* __restrict__ partials, const float* __restrict__ target,
    float* __restrict__ out) {
  __shared__ double red[4];
  double s = 0.0;
  for (int i = threadIdx.x; i < NWAVES; i += 256) s += partials[i];
#pragma unroll
  for (int off = 32; off > 0; off >>= 1) s += __shfl_down(s, off, 64);
  int wave = threadIdx.x >> 6, lane = threadIdx.x & 63;
  if (lane == 0) red[wave] = s;
  __syncthreads();
  if (threadIdx.x == 0) {
    double tot = red[0] + red[1] + red[2] + red[3];
    double mf  = 2.0 * tot / ((double)N * (double)(N - 1) * (double)T);
    double r   = mf - (double)target[0];
    out[0] = (float)(r > 0.0 ? r : 0.0);
  }
}

extern "C" void kernel_launch(void* const* d_in, const int* in_sizes, int n_in,
                              void* d_out, int out_size, void* d_ws, size_t ws_size,
                              hipStream_t stream) {
  const float* target = (const float*)d_in[0];
  const float* pred   = (const float*)d_in[1];
  const float* X      = (const float*)d_in[2];
  // d_in[3] = ntimes (==32, hardcoded); d_in[4] = scale
  const float* scale  = (const float*)d_in[4];

  double* partials = (double*)d_ws;  // NWAVES doubles, all written every call

  pair_kernel<<<dim3(NWAVES), dim3(64), 0, stream>>>(pred, X, scale, partials);
  finalize_kernel<<<dim3(1), dim3(256), 0, stream>>>(partials, target,
                                                     (float*)d_out);
}

// Round 10
// 80.256 us; speedup vs baseline: 1.2878x; 1.0835x over previous
//
#include <hip/hip_runtime.h>

#define N 2048
#define T 32
#define D 128
#define BT 32
#define MT (N / BT)                // 64 row-blocks
#define NTILES (MT * (MT + 1) / 2) // 2080 upper-triangular 32x32 tiles
#define NWAVES (2 * NTILES)        // 4160 half-tile (16x32) single-wave blocks
#define PSTR 33                    // LDS row stride (32 data + 1)

typedef float floatx4 __attribute__((ext_vector_type(4)));
typedef short bf16x8 __attribute__((ext_vector_type(8)));

// s_waitcnt lgkmcnt(0) only — 0xc07f. Single-wave WG: no barrier ever.
#define LGKM0() __builtin_amdgcn_s_waitcnt(0xc07f)

// tile id -> (a,b), a<=b, upper-triangular over MT x MT
__device__ __forceinline__ void tile_decode(int t, int& a, int& b) {
  a = (int)((2 * MT + 1 -
             sqrtf((float)((2 * MT + 1) * (2 * MT + 1) - 8 * t))) * 0.5f);
  while (a > 0 && t < a * MT - a * (a - 1) / 2) --a;
  while (t >= (a + 1) * MT - (a + 1) * a / 2) ++a;
  b = a + (t - (a * MT - a * (a - 1) / 2));
}

// ---------------------------------------------------------------------------
// Kernel 1: normalize each X row, split into truncated-bf16 h/l planes
// (xn = h + l + eps, hh+hl+lh Gram error <= 2^-16 rel — absmax 0.0 in R7),
// and store in MFMA-TILED layout:
//   plane[rb*2048 + ks*512 + q*128 + m*8 + j]  (shorts)
// so a pair-kernel fragment load (lanes = (m,q)) is one fully-coalesced
// 1 KB wave-read — R9's row-per-lane pattern cost ~64 cache-line requests
// per load instruction (the suspected shared-pipe serializer).
// One 64-thread wave per 16-row block; lane (m,q) owns row 16rb+m,
// cols {q*8 + ks*32}.
// ---------------------------------------------------------------------------
__global__ __launch_bounds__(64) void presplit_kernel(
    const float* __restrict__ X, unsigned short* __restrict__ hXt,
    unsigned short* __restrict__ lXt) {
  const int rb   = blockIdx.x;          // 0..127
  const int lane = threadIdx.x;
  const int m    = lane & 15;
  const int q    = lane >> 4;

  const float* xr = X + (size_t)(16 * rb + m) * D + q * 8;
  float4 v0[4], v1[4];
  float ss = 0.0f;
#pragma unroll
  for (int ks = 0; ks < 4; ++ks) {
    v0[ks] = *(const float4*)(xr + ks * 32);
    v1[ks] = *(const float4*)(xr + ks * 32 + 4);
    ss += v0[ks].x * v0[ks].x + v0[ks].y * v0[ks].y +
          v0[ks].z * v0[ks].z + v0[ks].w * v0[ks].w +
          v1[ks].x * v1[ks].x + v1[ks].y * v1[ks].y +
          v1[ks].z * v1[ks].z + v1[ks].w * v1[ks].w;
  }
  // row sumsq: lanes m, m+16, m+32, m+48 hold the 4 col-quads of row m
  ss += __shfl_xor(ss, 16, 64);
  ss += __shfl_xor(ss, 32, 64);
  const float rn = rsqrtf(ss);

#pragma unroll
  for (int ks = 0; ks < 4; ++ks) {
    bf16x8 h, l;
    float v[8] = {v0[ks].x, v0[ks].y, v0[ks].z, v0[ks].w,
                  v1[ks].x, v1[ks].y, v1[ks].z, v1[ks].w};
#pragma unroll
    for (int i = 0; i < 8; ++i) {
      const float a = v[i] * rn;
      const unsigned u = __float_as_uint(a);
      h[i] = (short)(u >> 16);
      const float lo = a - __uint_as_float(u & 0xffff0000u);  // exact
      l[i] = (short)(__float_as_uint(lo) >> 16);
    }
    const size_t o = (size_t)rb * 2048 + ks * 512 + q * 128 + m * 8;
    *(bf16x8*)(hXt + o) = h;
    *(bf16x8*)(lXt + o) = l;
  }
}

// ---------------------------------------------------------------------------
// Kernel 2: one 16x32 half-tile per single-wave block (R9 structure).
// Dot phase now: 24 fully-coalesced b128 loads + 24 MFMA — zero split VALU,
// zero norms (inputs pre-normalized). sd = scale*(1 - G). Hinge unchanged.
// Per-block partials to distinct addresses (no atomics — R8's regression).
// ---------------------------------------------------------------------------
__global__ __launch_bounds__(64) void pair_kernel(
    const float* __restrict__ pred,          // [N][T]
    const unsigned short* __restrict__ hXt,  // tiled bf16 high plane
    const unsigned short* __restrict__ lXt,  // tiled bf16 low plane
    const float* __restrict__ scale_p,       // [1]
    double* __restrict__ partials) {         // [NWAVES]
  __shared__ float P[48 * PSTR];             // 16 A-pred rows + 32 B-pred rows

  const int lane = threadIdx.x;
  const int w    = blockIdx.x;
  const int tile = w >> 1;
  const int h    = w & 1;                    // half: A-rows 16h..16h+15

  int a, b;
  tile_decode(tile, a, b);
  const int aRow0 = a * BT, bRow0 = b * BT;
  const int m    = lane & 15;
  const int quad = lane >> 4;
  const float scale = scale_p[0];

  // ---- stage 48 pred rows: 384 float4 chunks / 64 lanes = 6 each
#pragma unroll
  for (int s = 0; s < 6; ++s) {
    const int idx = s * 64 + lane;
    const int row = idx >> 3;
    const int fo  = (idx & 7) * 4;
    const int grow = (row < 16) ? (aRow0 + 16 * h + row) : (bRow0 + row - 16);
    *(float4*)(&P[row * PSTR + fo]) =
        *(const float4*)(pred + (size_t)grow * T + fo);
  }

  // ---- Gram half-tile via split-bf16 MFMA, tiled coalesced fragment loads
  floatx4 accf[2];
  accf[0] = (floatx4){0.f, 0.f, 0.f, 0.f};
  accf[1] = (floatx4){0.f, 0.f, 0.f, 0.f};

  const int arb = aRow0 / 16 + h;            // A 16-row block
  const int brb = bRow0 / 16;                // B 16-row blocks: brb, brb+1
  const size_t fo = (size_t)quad * 128 + m * 8;
  const unsigned short* pa_h = hXt + (size_t)arb * 2048 + fo;
  const unsigned short* pa_l = lXt + (size_t)arb * 2048 + fo;
  const unsigned short* pb_h = hXt + (size_t)brb * 2048 + fo;
  const unsigned short* pb_l = lXt + (size_t)brb * 2048 + fo;

#pragma unroll
  for (int ks = 0; ks < 4; ++ks) {
    bf16x8 hA, lA, hB[2], lB[2];
    hA = *(const bf16x8*)(pa_h + ks * 512);
    lA = *(const bf16x8*)(pa_l + ks * 512);
#pragma unroll
    for (int J = 0; J < 2; ++J) {
      hB[J] = *(const bf16x8*)(pb_h + (size_t)J * 2048 + ks * 512);
      lB[J] = *(const bf16x8*)(pb_l + (size_t)J * 2048 + ks * 512);
    }
#pragma unroll
    for (int J = 0; J < 2; ++J) {
      accf[J] = __builtin_amdgcn_mfma_f32_16x16x32_bf16(hA, hB[J], accf[J], 0, 0, 0);
      accf[J] = __builtin_amdgcn_mfma_f32_16x16x32_bf16(hA, lB[J], accf[J], 0, 0, 0);
      accf[J] = __builtin_amdgcn_mfma_f32_16x16x32_bf16(lA, hB[J], accf[J], 0, 0, 0);
    }
  }

  // ---- sd = scale*(1 - G); C layout: row = quad*4+r, col = 16J+m
  float sd[2][4], ps[2][4];
#pragma unroll
  for (int J = 0; J < 2; ++J)
#pragma unroll
    for (int r = 0; r < 4; ++r) {
      sd[J][r] = scale * (1.0f - accf[J][r]);
      ps[J][r] = 0.0f;
    }
  LGKM0();  // pred staging visible (single wave: DS in-order)

  // ---- hinge: sum_t max(|dp|, s); -32s correction under the mask
#pragma unroll
  for (int t4 = 0; t4 < 8; ++t4) {
    float4 qb[2];
    qb[0] = *(const float4*)(&P[(16 + m) * PSTR + t4 * 4]);
    qb[1] = *(const float4*)(&P[(32 + m) * PSTR + t4 * 4]);
#pragma unroll
    for (int r = 0; r < 4; ++r) {
      float4 qa = *(const float4*)(&P[(quad * 4 + r) * PSTR + t4 * 4]);
#pragma unroll
      for (int J = 0; J < 2; ++J) {
        float s = sd[J][r];
        ps[J][r] += fmaxf(fabsf(qa.x - qb[J].x), s) +
                    fmaxf(fabsf(qa.y - qb[J].y), s) +
                    fmaxf(fabsf(qa.z - qb[J].z), s) +
                    fmaxf(fabsf(qa.w - qb[J].w), s);
      }
    }
  }

  // ---- mask + correction + wave reduction
  float tsum = 0.0f;
#pragma unroll
  for (int J = 0; J < 2; ++J)
#pragma unroll
    for (int r = 0; r < 4; ++r) {
      const int ja   = aRow0 + 16 * h + quad * 4 + r;
      const int kcol = bRow0 + 16 * J + m;
      tsum += (kcol > ja) ? (ps[J][r] - 32.0f * sd[J][r]) : 0.0f;
    }

  double dsum = (double)tsum;
#pragma unroll
  for (int off = 32; off > 0; off >>= 1) dsum += __shfl_down(dsum, off, 64);
  if (lane == 0) partials[w] = dsum;
}

// ---------------------------------------------------------------------------
// Kernel 3: sum NWAVES partials, scale, clamp.
// ---------------------------------------------------------------------------
__global__ __launch_bounds__(256) void finalize_kernel(
    const double* __restrict__ partials, const float* __restrict__ target,
    float* __restrict__ out) {
  __shared__ double red[4];
  double s = 0.0;
  for (int i = threadIdx.x; i < NWAVES; i += 256) s += partials[i];
#pragma unroll
  for (int off = 32; off > 0; off >>= 1) s += __shfl_down(s, off, 64);
  int wave = threadIdx.x >> 6, lane = threadIdx.x & 63;
  if (lane == 0) red[wave] = s;
  __syncthreads();
  if (threadIdx.x == 0) {
    double tot = red[0] + red[1] + red[2] + red[3];
    double mf  = 2.0 * tot / ((double)N * (double)(N - 1) * (double)T);
    double r   = mf - (double)target[0];
    out[0] = (float)(r > 0.0 ? r : 0.0);
  }
}

extern "C" void kernel_launch(void* const* d_in, const int* in_sizes, int n_in,
                              void* d_out, int out_size, void* d_ws, size_t ws_size,
                              hipStream_t stream) {
  const float* target = (const float*)d_in[0];
  const float* pred   = (const float*)d_in[1];
  const float* X      = (const float*)d_in[2];
  // d_in[3] = ntimes (==32, hardcoded); d_in[4] = scale
  const float* scale  = (const float*)d_in[4];

  double*         partials = (double*)d_ws;                         // 33 KB
  unsigned short* hXt = (unsigned short*)((char*)d_ws + (1u << 20)); // 512 KB
  unsigned short* lXt = (unsigned short*)((char*)d_ws + (2u << 20)); // 512 KB

  presplit_kernel<<<dim3(D), dim3(64), 0, stream>>>(X, hXt, lXt);
  pair_kernel<<<dim3(NWAVES), dim3(64), 0, stream>>>(pred, hXt, lXt, scale,
                                                     partials);
  finalize_kernel<<<dim3(1), dim3(256), 0, stream>>>(partials, target,
                                                     (float*)d_out);
}